// Round 8
// baseline (250.259 us; speedup 1.0000x reference)
//
#include <hip/hip_runtime.h>

// Problem constants (fixed by the reference)
#define BATCH 256
#define CDIM  2048
#define HW    49
#define KDIM  16

#define OSTRIP 8                 // c-strips per image (conv) == c-chunks (bp)
#define SC     256               // c per strip
#define STRIP_B (SC * HW * 4)    // 50176 bytes per strip (== 49 * 1024)

// async global->LDS DMA, 16 B per lane: LDS dst = wave-uniform base + lane*16
// (linear), global src = per-lane address. Both 16B-aligned here.
#define GLDS(g, l) __builtin_amdgcn_global_load_lds(                        \
        (const __attribute__((address_space(1))) unsigned int*)(g),          \
        (__attribute__((address_space(3))) unsigned int*)(l), 16, 0, 0)

// Workspace (floats): wT[2048*16] at 0; pscr[256*784] at 32768 (~0.9 MB total).
//   prep inits pscr[b*784 + hw*16 + k] = shift[k]/49
//   conv atomicAdds its strip partial into the same slot (BN layout, final P_bn)

// ---------------------------------------------------------------------------
// prep: wT[c][k] = w16[k][c] * gamma[k]*rsqrt(var+eps)/49  (BN scale + pool folded)
//       pscr[b][hw][k] = (beta[k]-mean[k]*inv)/49          (BN shift pre-init)
// ---------------------------------------------------------------------------
__global__ __launch_bounds__(256) void prep_kernel(
    const float* __restrict__ w16,
    const float* __restrict__ gamma, const float* __restrict__ beta,
    const float* __restrict__ mean,  const float* __restrict__ var,
    float* __restrict__ wT, float* __restrict__ pscr)
{
    const int idx = blockIdx.x * 256 + threadIdx.x;   // grid 128 -> 32768 threads
    const int c = idx >> 4, k = idx & 15;
    const float inv = gamma[k] * rsqrtf(var[k] + 1e-5f) * (1.0f / 49.0f);
    wT[idx] = w16[k * CDIM + c] * inv;

    for (int i = idx; i < BATCH * (HW * KDIM); i += 128 * 256) {
        const int kk = i & 15;
        const float invk = gamma[kk] * rsqrtf(var[kk] + 1e-5f);
        pscr[i] = (beta[kk] - mean[kk] * invk) * (1.0f / 49.0f);
    }
}

// ---------------------------------------------------------------------------
// conv: pscr[b][hw][k] += sum_{c in strip} wT[c][k]*fm[c][hw]
// grid = BATCH*8, block = 256 (4 waves, 64 c per wave).
// fm strip (49 KB) streamed to LDS via global_load_lds DMA; reduction scratch
// ALIASES fbuf (barrier-separated) -> 50 KB LDS -> 3 blocks/CU resident, so
// one block's DMA streams under two blocks' compute.
// w read at wave-uniform addresses through __restrict__ global -> s_load.
// ---------------------------------------------------------------------------
__global__ __launch_bounds__(256) void conv_kernel(
    const float* __restrict__ fm, const float* __restrict__ wT,
    float* __restrict__ pscr)
{
    __shared__ __align__(16) float fbuf[SC * HW + 4];   // 50192 B; red aliases head

    const int tid  = threadIdx.x;
    const int b    = blockIdx.x >> 3;
    const int o    = blockIdx.x & 7;
    const int wavu = __builtin_amdgcn_readfirstlane(tid >> 6);  // wave-uniform
    const int lane = tid & 63;
    const int hwi  = lane < HW ? lane : HW - 1;  // clamp: lanes>=49 discarded

    // ---- DMA the strip into LDS: 49 x 1024B wave-loads, split 13/12/12/12 ----
    {
        const char* gbase = (const char*)fm
            + (size_t)b * (CDIM * HW * 4) + (size_t)o * STRIP_B;
        char* lbase = (char*)fbuf;
        const int nld = (wavu == 0) ? 13 : 12;
        for (int i = 0; i < nld; ++i) {
            const int j = wavu + 4 * i;                 // 0..48, wave-uniform
            GLDS(gbase + j * 1024 + lane * 16, lbase + j * 1024);
        }
    }
    __syncthreads();   // vmcnt(0) drained before barrier -> strip visible

    float acc[KDIM];
    #pragma unroll
    for (int k = 0; k < KDIM; ++k) acc[k] = 0.f;

    const int cl0 = wavu * 64;                          // wave's local c-base
    const float4* __restrict__ wq = (const float4*)(wT + (size_t)((o * SC + cl0) << 4));

    #pragma unroll 8
    for (int cc = 0; cc < 64; ++cc) {
        const float fv = fbuf[(cl0 + cc) * HW + hwi];   // ds_read_b32
        const float4 w0 = wq[cc * 4 + 0];               // uniform -> s_load
        const float4 w1 = wq[cc * 4 + 1];
        const float4 w2 = wq[cc * 4 + 2];
        const float4 w3 = wq[cc * 4 + 3];
        acc[0]  += w0.x * fv; acc[1]  += w0.y * fv; acc[2]  += w0.z * fv; acc[3]  += w0.w * fv;
        acc[4]  += w1.x * fv; acc[5]  += w1.y * fv; acc[6]  += w1.z * fv; acc[7]  += w1.w * fv;
        acc[8]  += w2.x * fv; acc[9]  += w2.y * fv; acc[10] += w2.z * fv; acc[11] += w2.w * fv;
        acc[12] += w3.x * fv; acc[13] += w3.y * fv; acc[14] += w3.z * fv; acc[15] += w3.w * fv;
    }

    __syncthreads();   // all fbuf reads done -> safe to alias as reduction scratch
    float* red = fbuf; // needs 4*16*52 = 3328 floats << 12548
    if (lane < HW) {
        #pragma unroll
        for (int k = 0; k < KDIM; ++k)
            red[wavu * (KDIM * 52) + k * 52 + lane] = acc[k];
    }
    __syncthreads();

    // cross-wave reduce + atomicAdd into BN layout pscr[b][hw][k]
    for (int p = tid; p < HW * KDIM; p += 256) {
        const int k = p / HW, hw = p - k * HW;
        const int a = k * 52 + hw;
        const float s = red[a] + red[a + 832] + red[a + 1664] + red[a + 2496];
        atomicAdd(&pscr[(size_t)b * 784 + hw * KDIM + k], s);
    }
}

// ---------------------------------------------------------------------------
// bp: out[b][k][c] = sum_hw P_bn[hw][k] * fm[c][hw]
// grid = BATCH*8 (256 c per block), block = 256, 1 c per thread.
// fm chunk (49 KB) staged via global_load_lds DMA (same 49x1024B pattern).
// P_bn block-uniform, never written here -> s_load (SGPR FMA operand).
// 50 KB LDS -> 3 blocks/CU: DMA of one block overlaps compute of others.
// ---------------------------------------------------------------------------
__global__ __launch_bounds__(256) void bp_kernel(
    const float* __restrict__ fm, const float* __restrict__ pscr,
    float* __restrict__ out)
{
    __shared__ __align__(16) float fs[SC * HW];      // 50176 B == 49*1024

    const int tid  = threadIdx.x;
    const int b    = blockIdx.x >> 3;
    const int oc   = (blockIdx.x & 7) * SC;
    const int wavu = __builtin_amdgcn_readfirstlane(tid >> 6);
    const int lane = tid & 63;

    // ---- DMA the c-chunk into LDS: identical strip shape to conv ----
    {
        const char* gbase = (const char*)fm + ((size_t)b * CDIM + oc) * (HW * 4);
        char* lbase = (char*)fs;
        const int nld = (wavu == 0) ? 13 : 12;
        for (int i = 0; i < nld; ++i) {
            const int j = wavu + 4 * i;
            GLDS(gbase + j * 1024 + lane * 16, lbase + j * 1024);
        }
    }
    __syncthreads();

    const float4* __restrict__ P4 = (const float4*)(pscr + (size_t)b * 784);

    float acc[KDIM];
    #pragma unroll
    for (int k = 0; k < KDIM; ++k) acc[k] = 0.f;

    const float* row = fs + tid * HW;                // stride 49 (odd) -> 2-way, free
    #pragma unroll
    for (int hw = 0; hw < HW; ++hw) {
        const float fv = row[hw];
        const float4 p0 = P4[hw * 4 + 0];            // uniform -> s_load
        const float4 p1 = P4[hw * 4 + 1];
        const float4 p2 = P4[hw * 4 + 2];
        const float4 p3 = P4[hw * 4 + 3];
        acc[0]  += p0.x * fv; acc[1]  += p0.y * fv; acc[2]  += p0.z * fv; acc[3]  += p0.w * fv;
        acc[4]  += p1.x * fv; acc[5]  += p1.y * fv; acc[6]  += p1.z * fv; acc[7]  += p1.w * fv;
        acc[8]  += p2.x * fv; acc[9]  += p2.y * fv; acc[10] += p2.z * fv; acc[11] += p2.w * fv;
        acc[12] += p3.x * fv; acc[13] += p3.y * fv; acc[14] += p3.z * fv; acc[15] += p3.w * fv;
    }

    float* ob = out + (size_t)b * (KDIM * CDIM) + oc + tid;
    #pragma unroll
    for (int k = 0; k < KDIM; ++k) ob[k * CDIM] = acc[k];
}

extern "C" void kernel_launch(void* const* d_in, const int* in_sizes, int n_in,
                              void* d_out, int out_size, void* d_ws, size_t ws_size,
                              hipStream_t stream) {
    const float* fm    = (const float*)d_in[0];
    const float* w16   = (const float*)d_in[1];
    const float* gamma = (const float*)d_in[2];
    const float* beta  = (const float*)d_in[3];
    const float* mean  = (const float*)d_in[4];
    const float* var   = (const float*)d_in[5];
    float* out  = (float*)d_out;
    float* wT   = (float*)d_ws;                   // 32768 floats (128 KB)
    float* pscr = (float*)d_ws + CDIM * KDIM;     // 256*784 floats (~0.78 MB)

    prep_kernel<<<128, 256, 0, stream>>>(w16, gamma, beta, mean, var, wT, pscr);
    conv_kernel<<<BATCH * OSTRIP, 256, 0, stream>>>(fm, wT, pscr);
    bp_kernel<<<BATCH * OSTRIP, 256, 0, stream>>>(fm, pscr, out);
}